// Round 1
// baseline (1747.577 us; speedup 1.0000x reference)
//
#include <hip/hip_runtime.h>

// max_valences table: {0:4,1:3,2:2,3:6,4:1,5:1,6:1,7:1,8:4,9:4,10:4}, default 4
__constant__ float c_maxv[11] = {4.f, 3.f, 2.f, 6.f, 1.f, 1.f, 1.f, 1.f, 4.f, 4.f, 4.f};

// Kernel 1: bond_counts histogram. Vectorized int4 edge reads, integer atomics
// into L2-resident 2 MB counter array (exact counts, no fp rounding).
__global__ __launch_bounds__(256) void count_kernel(const int* __restrict__ row,
                                                    unsigned int* __restrict__ counts,
                                                    int nvec, int E) {
    int i = blockIdx.x * 256 + threadIdx.x;
    if (i < nvec) {
        int4 r = reinterpret_cast<const int4*>(row)[i];
        atomicAdd(&counts[r.x], 1u);
        atomicAdd(&counts[r.y], 1u);
        atomicAdd(&counts[r.z], 1u);
        atomicAdd(&counts[r.w], 1u);
    }
    int e = nvec * 4 + i;  // tail (E not divisible by 4)
    if (e < E) atomicAdd(&counts[row[e]], 1u);
}

// Kernel 2 (fused): per-node violation + h scaling + violations reduction.
// One thread per float4 chunk of h; cpr = D/4 chunks per row. The chunk-0
// thread of each row contributes v^2; block-reduce (wave64 shuffle + LDS),
// one float atomicAdd per block.
__global__ __launch_bounds__(256) void scale_kernel(const float4* __restrict__ h,
                                                    const unsigned int* __restrict__ counts,
                                                    const int* __restrict__ atom_types,
                                                    float4* __restrict__ out,
                                                    float* __restrict__ viol,
                                                    int total, int cpr, float inv_n) {
    int idx = blockIdx.x * 256 + threadIdx.x;
    float contrib = 0.0f;
    if (idx < total) {
        int r = idx / cpr;        // D=128 -> cpr=32 (pow2, compiler folds to shift)
        int c = idx - r * cpr;
        int t = atom_types[r];    // L1-broadcast across the 32 threads of a row
        float maxv = (t >= 0 && t < 11) ? c_maxv[t] : 4.0f;
        float v = fmaxf((float)counts[r] - maxv, 0.0f);
        float s = 1.0f - 0.1f * v;
        float4 hv = h[idx];
        hv.x *= s; hv.y *= s; hv.z *= s; hv.w *= s;
        out[idx] = hv;
        if (c == 0) contrib = v * v;
    }
    // wave64 butterfly reduce
    for (int off = 32; off > 0; off >>= 1)
        contrib += __shfl_down(contrib, off, 64);
    __shared__ float sdata[4];
    if ((threadIdx.x & 63) == 0) sdata[threadIdx.x >> 6] = contrib;
    __syncthreads();
    if (threadIdx.x == 0)
        atomicAdd(viol, (sdata[0] + sdata[1] + sdata[2] + sdata[3]) * inv_n);
}

extern "C" void kernel_launch(void* const* d_in, const int* in_sizes, int n_in,
                              void* d_out, int out_size, void* d_ws, size_t ws_size,
                              hipStream_t stream) {
    // inputs: h (N*D f32), edge_index (2*E int32), predicted_valences (N f32, UNUSED),
    //         atom_types (N int32)
    const float* h          = (const float*)d_in[0];
    const int*   edge       = (const int*)d_in[1];   // row = edge[0..E-1]
    const int*   atom_types = (const int*)d_in[3];

    int N = in_sizes[3];
    int D = in_sizes[0] / N;        // 128
    int E = in_sizes[1] / 2;        // 16M

    unsigned int* counts = (unsigned int*)d_ws;       // N * 4 B = 2 MB scratch
    float* out  = (float*)d_out;                      // h_out: N*D floats
    float* viol = out + (size_t)N * (size_t)D;        // violations scalar (last elem)

    // zero-init (d_ws / d_out are poisoned 0xAA before every call)
    hipMemsetAsync(counts, 0, (size_t)N * sizeof(unsigned int), stream);
    hipMemsetAsync(viol, 0, sizeof(float), stream);

    int nvec = E / 4;
    int cblocks = (nvec + 255) / 256;
    count_kernel<<<cblocks, 256, 0, stream>>>(edge, counts, nvec, E);

    int cpr = D / 4;
    int total = N * cpr;            // 16M, fits int32
    int sblocks = (total + 255) / 256;
    scale_kernel<<<sblocks, 256, 0, stream>>>((const float4*)h, counts, atom_types,
                                              (float4*)out, viol, total, cpr,
                                              1.0f / (float)N);
}

// Round 2
// 1070.814 us; speedup vs baseline: 1.6320x; 1.6320x over previous
//
#include <hip/hip_runtime.h>

// max_valences table: {0:4,1:3,2:2,3:6,4:1,5:1,6:1,7:1,8:4,9:4,10:4}, default 4
__constant__ float c_maxv[11] = {4.f, 3.f, 2.f, 6.f, 1.f, 1.f, 1.f, 1.f, 4.f, 4.f, 4.f};

#define NREP 8  // counter replicas; blockIdx&7 ~ XCD id under round-robin dispatch

// Kernel A: replicated histogram. Each block atomics into replica (blockIdx&7),
// keeping counter lines XCD-local (and cutting per-address contention 8x).
__global__ __launch_bounds__(256) void count_kernel(const int* __restrict__ row,
                                                    unsigned int* __restrict__ counts,
                                                    int nvec, int E, int N) {
    unsigned int* my = counts + (size_t)(blockIdx.x & (NREP - 1)) * (size_t)N;
    int i = blockIdx.x * 256 + threadIdx.x;
    if (i < nvec) {
        int4 r = reinterpret_cast<const int4*>(row)[i];
        atomicAdd(&my[r.x], 1u);
        atomicAdd(&my[r.y], 1u);
        atomicAdd(&my[r.z], 1u);
        atomicAdd(&my[r.w], 1u);
    }
    int e = nvec * 4 + i;  // tail (if E % 4 != 0)
    if (e < E) atomicAdd(&my[row[e]], 1u);
}

// Kernel B: per-node epilogue. Sum the 8 replicas, compute violation v,
// store scale s[r] = 1 - 0.1 v, block-reduce v^2, one atomic per block
// (fixed small grid -> ~512 atomics total, negligible).
__global__ __launch_bounds__(256) void node_kernel(const unsigned int* __restrict__ counts,
                                                   const int* __restrict__ atom_types,
                                                   float* __restrict__ sarr,
                                                   float* __restrict__ viol,
                                                   int N, float inv_n) {
    int stride = gridDim.x * 256;
    float local = 0.0f;
    for (int r = blockIdx.x * 256 + threadIdx.x; r < N; r += stride) {
        unsigned int c = 0;
        #pragma unroll
        for (int k = 0; k < NREP; ++k) c += counts[(size_t)k * (size_t)N + r];
        int t = atom_types[r];
        float maxv = (t >= 0 && t < 11) ? c_maxv[t] : 4.0f;
        float v = fmaxf((float)c - maxv, 0.0f);
        sarr[r] = 1.0f - 0.1f * v;
        local += v * v;
    }
    // wave64 butterfly + LDS block reduce
    for (int off = 32; off > 0; off >>= 1)
        local += __shfl_down(local, off, 64);
    __shared__ float sdata[4];
    if ((threadIdx.x & 63) == 0) sdata[threadIdx.x >> 6] = local;
    __syncthreads();
    if (threadIdx.x == 0)
        atomicAdd(viol, (sdata[0] + sdata[1] + sdata[2] + sdata[3]) * inv_n);
}

// Kernel C: pure stream, no atomics: out[idx] = h[idx] * s[row]. Grid-stride.
__global__ __launch_bounds__(256) void scale_kernel(const float4* __restrict__ h,
                                                    const float* __restrict__ sarr,
                                                    float4* __restrict__ out,
                                                    int total, int cpr_shift) {
    int stride = gridDim.x * 256;
    for (int idx = blockIdx.x * 256 + threadIdx.x; idx < total; idx += stride) {
        float s = sarr[idx >> cpr_shift];   // D=128 -> 32 float4/row -> shift 5
        float4 hv = h[idx];
        hv.x *= s; hv.y *= s; hv.z *= s; hv.w *= s;
        out[idx] = hv;
    }
}

extern "C" void kernel_launch(void* const* d_in, const int* in_sizes, int n_in,
                              void* d_out, int out_size, void* d_ws, size_t ws_size,
                              hipStream_t stream) {
    // inputs: h (N*D f32), edge_index (2*E int), predicted_valences (N f32, UNUSED),
    //         atom_types (N int)
    const float* h          = (const float*)d_in[0];
    const int*   edge       = (const int*)d_in[1];   // row = edge[0..E-1]
    const int*   atom_types = (const int*)d_in[3];

    int N = in_sizes[3];
    int D = in_sizes[0] / N;        // 128
    int E = in_sizes[1] / 2;        // 16M

    // ws layout: [NREP * N uint counts][N float scales]
    unsigned int* counts = (unsigned int*)d_ws;                  // 16 MB
    float* sarr = (float*)((char*)d_ws + (size_t)NREP * N * 4);  // 2 MB
    float* out  = (float*)d_out;
    float* viol = out + (size_t)N * (size_t)D;

    hipMemsetAsync(counts, 0, (size_t)NREP * N * sizeof(unsigned int), stream);
    hipMemsetAsync(viol, 0, sizeof(float), stream);

    int nvec = E / 4;
    int cblocks = (nvec + 255) / 256;
    count_kernel<<<cblocks, 256, 0, stream>>>(edge, counts, nvec, E, N);

    node_kernel<<<512, 256, 0, stream>>>(counts, atom_types, sarr, viol, N,
                                         1.0f / (float)N);

    int cpr = D / 4;                 // 32
    int cpr_shift = 0; while ((1 << cpr_shift) < cpr) ++cpr_shift;  // 5 for D=128
    int total = N * cpr;             // 16M
    scale_kernel<<<8192, 256, 0, stream>>>((const float4*)h, sarr,
                                           (float4*)out, total, cpr_shift);
}